// Round 1
// baseline (456.176 us; speedup 1.0000x reference)
//
#include <hip/hip_runtime.h>

#define N_NODES 50000
#define N_EDGES 800000
#define IN_F 256
#define OUT_F 128

typedef __attribute__((ext_vector_type(8))) short short8;
typedef __attribute__((ext_vector_type(4))) float float4_t;

// float -> bf16 round-to-nearest-even
__device__ __forceinline__ short f2bf(float f) {
  unsigned u = __builtin_bit_cast(unsigned, f);
  u = u + 0x7FFFu + ((u >> 16) & 1u);
  return (short)(u >> 16);
}

__global__ void init_kernel(int* __restrict__ deg, int* __restrict__ cnt) {
  int i = blockIdx.x * 256 + threadIdx.x;
  if (i < N_NODES) { deg[i] = 0; cnt[i] = 0; }
}

__global__ void count_kernel(const int* __restrict__ src, const int* __restrict__ dst,
                             int* __restrict__ deg, int* __restrict__ cnt) {
  int e = blockIdx.x * 256 + threadIdx.x;
  if (e < N_EDGES) {
    atomicAdd(&deg[src[e]], 1);
    atomicAdd(&cnt[dst[e]], 1);
  }
}

// single-block exclusive scan of cnt -> row_off/cursor; also norm = 1/max(deg,1)
__global__ __launch_bounds__(1024) void scan_kernel(const int* __restrict__ cnt,
                                                    const int* __restrict__ deg,
                                                    int* __restrict__ row_off,
                                                    int* __restrict__ cursor,
                                                    float* __restrict__ norm) {
  __shared__ int sd[1024];
  int t = threadIdx.x;
  const int C = (N_NODES + 1023) / 1024;  // 49
  int start = t * C;
  int end = start + C; if (end > N_NODES) end = N_NODES;
  int sum = 0;
  for (int i = start; i < end && i < N_NODES; ++i) sum += cnt[i];
  sd[t] = sum;
  __syncthreads();
  for (int off = 1; off < 1024; off <<= 1) {
    int v = 0;
    if (t >= off) v = sd[t - off];
    __syncthreads();
    if (t >= off) sd[t] += v;
    __syncthreads();
  }
  int running = sd[t] - sum;  // exclusive prefix
  for (int i = start; i < end && i < N_NODES; ++i) {
    row_off[i] = running;
    cursor[i] = running;
    running += cnt[i];
    int dg = deg[i];
    norm[i] = 1.0f / (float)(dg > 1 ? dg : 1);
  }
  if (start < N_NODES && end == N_NODES) row_off[N_NODES] = running;
}

__global__ void scatter_kernel(const int* __restrict__ src, const int* __restrict__ dst,
                               int* __restrict__ cursor, int* __restrict__ eidx) {
  int e = blockIdx.x * 256 + threadIdx.x;
  if (e < N_EDGES) {
    int p = atomicAdd(&cursor[dst[e]], 1);
    eidx[p] = src[e];
  }
}

// W [256][128] fp32 row-major -> bf16 in MFMA B-fragment order:
// Wf[ ((s*8+t)*16 + m)*32 + q*8 + j ]  where k=s*32+q*8+j, n=t*16+m
__global__ void wprep_kernel(const float* __restrict__ W, short* __restrict__ Wf) {
  int idx = blockIdx.x * 256 + threadIdx.x;  // 32768 total
  int k = idx >> 7, n = idx & 127;
  int s = k >> 5, q = (k >> 3) & 3, j = k & 7;
  int t = n >> 4, m = n & 15;
  Wf[(((s * 8 + t) * 16 + m) * 32) + q * 8 + j] = f2bf(W[idx]);
}

// h = (feat @ W) * norm[row], stored as bf16 (ushort). No LDS.
// Block: 256 thr = 4 waves; wave handles 32 rows x 128 cols (2 m-subtiles x 8 n-tiles).
__global__ __launch_bounds__(256) void gemm_kernel(const float* __restrict__ feat,
                                                   const short* __restrict__ Wf,
                                                   const float* __restrict__ norm,
                                                   unsigned short* __restrict__ h) {
  int tid = threadIdx.x;
  int w = tid >> 6, l = tid & 63;
  int m = l & 15, q = l >> 4;
  long base = (long)blockIdx.x * 128 + w * 32;

  float4_t acc[2][8];
#pragma unroll
  for (int r = 0; r < 2; ++r)
#pragma unroll
    for (int t = 0; t < 8; ++t) acc[r][t] = (float4_t)(0.0f);

  long row0 = base + m;
  long row1 = base + 16 + m;
  long r0c = row0 < N_NODES - 1 ? row0 : N_NODES - 1;
  long r1c = row1 < N_NODES - 1 ? row1 : N_NODES - 1;
  const float* a0p = feat + (size_t)r0c * IN_F;
  const float* a1p = feat + (size_t)r1c * IN_F;
  const short8* bb = (const short8*)Wf;

#pragma unroll
  for (int s = 0; s < 8; ++s) {
    int k0 = s * 32 + q * 8;
    float4_t av0a = *(const float4_t*)(a0p + k0);
    float4_t av0b = *(const float4_t*)(a0p + k0 + 4);
    float4_t av1a = *(const float4_t*)(a1p + k0);
    float4_t av1b = *(const float4_t*)(a1p + k0 + 4);
    short8 fa0, fa1;
#pragma unroll
    for (int i = 0; i < 4; ++i) {
      fa0[i] = f2bf(av0a[i]);
      fa0[i + 4] = f2bf(av0b[i]);
      fa1[i] = f2bf(av1a[i]);
      fa1[i + 4] = f2bf(av1b[i]);
    }
#pragma unroll
    for (int t = 0; t < 8; ++t) {
      short8 fb = bb[((s * 8 + t) * 16 + m) * 4 + q];
      acc[0][t] = __builtin_amdgcn_mfma_f32_16x16x32_bf16(fa0, fb, acc[0][t], 0, 0, 0);
      acc[1][t] = __builtin_amdgcn_mfma_f32_16x16x32_bf16(fa1, fb, acc[1][t], 0, 0, 0);
    }
  }

  // C/D layout: col = lane&15 (=m), row = q*4 + i
#pragma unroll
  for (int r = 0; r < 2; ++r) {
#pragma unroll
    for (int i = 0; i < 4; ++i) {
      long row = base + r * 16 + q * 4 + i;
      if (row < N_NODES) {
        float nm = norm[row];
        size_t ho = (size_t)row * OUT_F;
#pragma unroll
        for (int t = 0; t < 8; ++t) {
          h[ho + t * 16 + m] = (unsigned short)f2bf(acc[r][t][i] * nm);
        }
      }
    }
  }
}

// One wave per dst node. Lane covers 2 columns (one uint = 2 bf16 of h row).
__global__ __launch_bounds__(256) void agg_kernel(const unsigned short* __restrict__ h,
                                                  const int* __restrict__ row_off,
                                                  const int* __restrict__ eidx,
                                                  const float* __restrict__ bias,
                                                  float* __restrict__ out) {
  int w = threadIdx.x >> 6, l = threadIdx.x & 63;
  int d = blockIdx.x * 4 + w;  // grid 12500 -> exactly 50000
  int rs = row_off[d], re = row_off[d + 1];
  const unsigned* __restrict__ hu = (const unsigned*)h;  // 64 uints per row
  float a0 = 0.0f, a1 = 0.0f;
  for (int bse = rs; bse < re; bse += 64) {
    int n = re - bse; if (n > 64) n = 64;
    int e = (l < n) ? eidx[bse + l] : 0;
    int j = 0;
    for (; j + 4 <= n; j += 4) {
      int s0 = __shfl(e, j);
      int s1 = __shfl(e, j + 1);
      int s2 = __shfl(e, j + 2);
      int s3 = __shfl(e, j + 3);
      unsigned v0 = hu[(size_t)s0 * 64 + l];
      unsigned v1 = hu[(size_t)s1 * 64 + l];
      unsigned v2 = hu[(size_t)s2 * 64 + l];
      unsigned v3 = hu[(size_t)s3 * 64 + l];
      a0 += __builtin_bit_cast(float, v0 << 16);
      a1 += __builtin_bit_cast(float, v0 & 0xFFFF0000u);
      a0 += __builtin_bit_cast(float, v1 << 16);
      a1 += __builtin_bit_cast(float, v1 & 0xFFFF0000u);
      a0 += __builtin_bit_cast(float, v2 << 16);
      a1 += __builtin_bit_cast(float, v2 & 0xFFFF0000u);
      a0 += __builtin_bit_cast(float, v3 << 16);
      a1 += __builtin_bit_cast(float, v3 & 0xFFFF0000u);
    }
    for (; j < n; ++j) {
      int s0 = __shfl(e, j);
      unsigned v0 = hu[(size_t)s0 * 64 + l];
      a0 += __builtin_bit_cast(float, v0 << 16);
      a1 += __builtin_bit_cast(float, v0 & 0xFFFF0000u);
    }
  }
  float2 b = ((const float2*)bias)[l];
  float2 o;
  o.x = a0 + b.x;
  o.y = a1 + b.y;
  ((float2*)(out + (size_t)d * OUT_F))[l] = o;
}

extern "C" void kernel_launch(void* const* d_in, const int* in_sizes, int n_in,
                              void* d_out, int out_size, void* d_ws, size_t ws_size,
                              hipStream_t stream) {
  const float* feat = (const float*)d_in[0];
  const float* weight = (const float*)d_in[1];
  const float* bias = (const float*)d_in[2];
  const int* src = (const int*)d_in[3];
  const int* dst = (const int*)d_in[4];
  float* out = (float*)d_out;

  char* ws = (char*)d_ws;
  size_t off = 0;
  auto alloc = [&](size_t bytes) -> void* {
    void* p = ws + off;
    off += (bytes + 511) & ~(size_t)511;
    return p;
  };
  int* deg = (int*)alloc(N_NODES * 4);
  int* cnt = (int*)alloc(N_NODES * 4);
  int* row_off = (int*)alloc((N_NODES + 1) * 4);
  int* cursor = (int*)alloc(N_NODES * 4);
  float* norm = (float*)alloc(N_NODES * 4);
  int* eidx = (int*)alloc(N_EDGES * 4);
  short* Wf = (short*)alloc(IN_F * OUT_F * 2);
  unsigned short* h = (unsigned short*)alloc((size_t)N_NODES * OUT_F * 2);
  (void)off; (void)ws_size; (void)in_sizes; (void)n_in; (void)out_size;

  hipLaunchKernelGGL(init_kernel, dim3((N_NODES + 255) / 256), dim3(256), 0, stream, deg, cnt);
  hipLaunchKernelGGL(count_kernel, dim3(N_EDGES / 256), dim3(256), 0, stream, src, dst, deg, cnt);
  hipLaunchKernelGGL(scan_kernel, dim3(1), dim3(1024), 0, stream, cnt, deg, row_off, cursor, norm);
  hipLaunchKernelGGL(scatter_kernel, dim3(N_EDGES / 256), dim3(256), 0, stream, src, dst, cursor, eidx);
  hipLaunchKernelGGL(wprep_kernel, dim3((IN_F * OUT_F) / 256), dim3(256), 0, stream, weight, Wf);
  hipLaunchKernelGGL(gemm_kernel, dim3((N_NODES + 127) / 128), dim3(256), 0, stream, feat, Wf, norm, h);
  hipLaunchKernelGGL(agg_kernel, dim3(N_NODES / 4), dim3(256), 0, stream, h, row_off, eidx, bias, out);
}

// Round 2
// 269.691 us; speedup vs baseline: 1.6915x; 1.6915x over previous
//
#include <hip/hip_runtime.h>

#define N_NODES 50000
#define N_EDGES 800000
#define IN_F 256
#define OUT_F 128
#define SCAN_BLOCKS 49  // ceil(50000/1024)

typedef __attribute__((ext_vector_type(8))) short short8;
typedef __attribute__((ext_vector_type(4))) float float4_t;

// float -> bf16 round-to-nearest-even
__device__ __forceinline__ short f2bf(float f) {
  unsigned u = __builtin_bit_cast(unsigned, f);
  u = u + 0x7FFFu + ((u >> 16) & 1u);
  return (short)(u >> 16);
}

__global__ void init_kernel(int* __restrict__ deg, int* __restrict__ cnt) {
  int i = blockIdx.x * 256 + threadIdx.x;
  if (i < N_NODES) { deg[i] = 0; cnt[i] = 0; }
}

__global__ void count_kernel(const int* __restrict__ src, const int* __restrict__ dst,
                             int* __restrict__ deg, int* __restrict__ cnt) {
  int e = blockIdx.x * 256 + threadIdx.x;
  if (e < N_EDGES) {
    atomicAdd(&deg[src[e]], 1);
    atomicAdd(&cnt[dst[e]], 1);
  }
}

// ---- 3-phase parallel scan of cnt -> row_off/cursor (+ norm from deg) ----
__global__ __launch_bounds__(256) void blocksum_kernel(const int* __restrict__ cnt,
                                                       int* __restrict__ blockSums) {
  int t = threadIdx.x, b = blockIdx.x;
  int base = b * 1024 + t * 4;
  int s = 0;
#pragma unroll
  for (int i = 0; i < 4; ++i) {
    int idx = base + i;
    if (idx < N_NODES) s += cnt[idx];
  }
  for (int off = 32; off > 0; off >>= 1) s += __shfl_down(s, off);
  __shared__ int ws[4];
  int l = t & 63, w = t >> 6;
  if (l == 0) ws[w] = s;
  __syncthreads();
  if (t == 0) blockSums[b] = ws[0] + ws[1] + ws[2] + ws[3];
}

__global__ void scanblocks_kernel(const int* __restrict__ blockSums,
                                  int* __restrict__ blockOff) {
  int l = threadIdx.x;  // 64 threads
  int v = (l < SCAN_BLOCKS) ? blockSums[l] : 0;
  int x = v;
  for (int off = 1; off < 64; off <<= 1) {
    int y = __shfl_up(x, off);
    if (l >= off) x += y;
  }
  if (l < SCAN_BLOCKS) blockOff[l] = x - v;  // exclusive
}

__global__ __launch_bounds__(256) void csr_kernel(const int* __restrict__ cnt,
                                                  const int* __restrict__ deg,
                                                  const int* __restrict__ blockOff,
                                                  int* __restrict__ row_off,
                                                  int* __restrict__ cursor,
                                                  float* __restrict__ norm) {
  int t = threadIdx.x, b = blockIdx.x;
  int base = b * 1024 + t * 4;
  int v[4];
  int s = 0;
#pragma unroll
  for (int i = 0; i < 4; ++i) {
    int idx = base + i;
    v[i] = (idx < N_NODES) ? cnt[idx] : 0;
    s += v[i];
  }
  int l = t & 63, w = t >> 6;
  int x = s;
  for (int off = 1; off < 64; off <<= 1) {
    int y = __shfl_up(x, off);
    if (l >= off) x += y;
  }
  __shared__ int ws[4];
  if (l == 63) ws[w] = x;
  __syncthreads();
  int wadd = 0;
  for (int i = 0; i < w; ++i) wadd += ws[i];
  int run = blockOff[b] + wadd + x - s;  // exclusive prefix of this thread's chunk
#pragma unroll
  for (int i = 0; i < 4; ++i) {
    int idx = base + i;
    if (idx < N_NODES) {
      row_off[idx] = run;
      cursor[idx] = run;
      run += v[i];
      int dg = deg[idx];
      norm[idx] = 1.0f / (float)(dg > 1 ? dg : 1);
      if (idx == N_NODES - 1) row_off[N_NODES] = run;
    }
  }
}

__global__ void scatter_kernel(const int* __restrict__ src, const int* __restrict__ dst,
                               int* __restrict__ cursor, int* __restrict__ eidx) {
  int e = blockIdx.x * 256 + threadIdx.x;
  if (e < N_EDGES) {
    int p = atomicAdd(&cursor[dst[e]], 1);
    eidx[p] = src[e];
  }
}

// W [256][128] fp32 row-major -> bf16 in MFMA B-fragment order:
// Wf[ ((s*8+t)*16 + m)*32 + q*8 + j ]  where k=s*32+q*8+j, n=t*16+m
__global__ void wprep_kernel(const float* __restrict__ W, short* __restrict__ Wf) {
  int idx = blockIdx.x * 256 + threadIdx.x;  // 32768 total
  int k = idx >> 7, n = idx & 127;
  int s = k >> 5, q = (k >> 3) & 3, j = k & 7;
  int t = n >> 4, m = n & 15;
  Wf[(((s * 8 + t) * 16 + m) * 32) + q * 8 + j] = f2bf(W[idx]);
}

// h = (feat @ W) * norm[row], stored as bf16 (ushort). No LDS.
// Block: 256 thr = 4 waves; wave handles 32 rows x 128 cols (2 m-subtiles x 8 n-tiles).
__global__ __launch_bounds__(256) void gemm_kernel(const float* __restrict__ feat,
                                                   const short* __restrict__ Wf,
                                                   const float* __restrict__ norm,
                                                   unsigned short* __restrict__ h) {
  int tid = threadIdx.x;
  int w = tid >> 6, l = tid & 63;
  int m = l & 15, q = l >> 4;
  long base = (long)blockIdx.x * 128 + w * 32;

  float4_t acc[2][8];
#pragma unroll
  for (int r = 0; r < 2; ++r)
#pragma unroll
    for (int t = 0; t < 8; ++t) acc[r][t] = (float4_t)(0.0f);

  long row0 = base + m;
  long row1 = base + 16 + m;
  long r0c = row0 < N_NODES - 1 ? row0 : N_NODES - 1;
  long r1c = row1 < N_NODES - 1 ? row1 : N_NODES - 1;
  const float* a0p = feat + (size_t)r0c * IN_F;
  const float* a1p = feat + (size_t)r1c * IN_F;
  const short8* bb = (const short8*)Wf;

#pragma unroll
  for (int s = 0; s < 8; ++s) {
    int k0 = s * 32 + q * 8;
    float4_t av0a = *(const float4_t*)(a0p + k0);
    float4_t av0b = *(const float4_t*)(a0p + k0 + 4);
    float4_t av1a = *(const float4_t*)(a1p + k0);
    float4_t av1b = *(const float4_t*)(a1p + k0 + 4);
    short8 fa0, fa1;
#pragma unroll
    for (int i = 0; i < 4; ++i) {
      fa0[i] = f2bf(av0a[i]);
      fa0[i + 4] = f2bf(av0b[i]);
      fa1[i] = f2bf(av1a[i]);
      fa1[i + 4] = f2bf(av1b[i]);
    }
#pragma unroll
    for (int t = 0; t < 8; ++t) {
      short8 fb = bb[((s * 8 + t) * 16 + m) * 4 + q];
      acc[0][t] = __builtin_amdgcn_mfma_f32_16x16x32_bf16(fa0, fb, acc[0][t], 0, 0, 0);
      acc[1][t] = __builtin_amdgcn_mfma_f32_16x16x32_bf16(fa1, fb, acc[1][t], 0, 0, 0);
    }
  }

  // C/D layout: col = lane&15 (=m), row = q*4 + i
#pragma unroll
  for (int r = 0; r < 2; ++r) {
#pragma unroll
    for (int i = 0; i < 4; ++i) {
      long row = base + r * 16 + q * 4 + i;
      if (row < N_NODES) {
        float nm = norm[row];
        size_t ho = (size_t)row * OUT_F;
#pragma unroll
        for (int t = 0; t < 8; ++t) {
          h[ho + t * 16 + m] = (unsigned short)f2bf(acc[r][t][i] * nm);
        }
      }
    }
  }
}

// One wave per dst node. Lane covers 2 columns (one uint = 2 bf16 of h row).
__global__ __launch_bounds__(256) void agg_kernel(const unsigned short* __restrict__ h,
                                                  const int* __restrict__ row_off,
                                                  const int* __restrict__ eidx,
                                                  const float* __restrict__ bias,
                                                  float* __restrict__ out) {
  int w = threadIdx.x >> 6, l = threadIdx.x & 63;
  int d = blockIdx.x * 4 + w;  // grid 12500 -> exactly 50000
  int rs = row_off[d], re = row_off[d + 1];
  const unsigned* __restrict__ hu = (const unsigned*)h;  // 64 uints per row
  float a0 = 0.0f, a1 = 0.0f;
  for (int bse = rs; bse < re; bse += 64) {
    int n = re - bse; if (n > 64) n = 64;
    int e = (l < n) ? eidx[bse + l] : 0;
    int j = 0;
    for (; j + 4 <= n; j += 4) {
      int s0 = __shfl(e, j);
      int s1 = __shfl(e, j + 1);
      int s2 = __shfl(e, j + 2);
      int s3 = __shfl(e, j + 3);
      unsigned v0 = hu[(size_t)s0 * 64 + l];
      unsigned v1 = hu[(size_t)s1 * 64 + l];
      unsigned v2 = hu[(size_t)s2 * 64 + l];
      unsigned v3 = hu[(size_t)s3 * 64 + l];
      a0 += __builtin_bit_cast(float, v0 << 16);
      a1 += __builtin_bit_cast(float, v0 & 0xFFFF0000u);
      a0 += __builtin_bit_cast(float, v1 << 16);
      a1 += __builtin_bit_cast(float, v1 & 0xFFFF0000u);
      a0 += __builtin_bit_cast(float, v2 << 16);
      a1 += __builtin_bit_cast(float, v2 & 0xFFFF0000u);
      a0 += __builtin_bit_cast(float, v3 << 16);
      a1 += __builtin_bit_cast(float, v3 & 0xFFFF0000u);
    }
    for (; j < n; ++j) {
      int s0 = __shfl(e, j);
      unsigned v0 = hu[(size_t)s0 * 64 + l];
      a0 += __builtin_bit_cast(float, v0 << 16);
      a1 += __builtin_bit_cast(float, v0 & 0xFFFF0000u);
    }
  }
  float2 b = ((const float2*)bias)[l];
  float2 o;
  o.x = a0 + b.x;
  o.y = a1 + b.y;
  ((float2*)(out + (size_t)d * OUT_F))[l] = o;
}

extern "C" void kernel_launch(void* const* d_in, const int* in_sizes, int n_in,
                              void* d_out, int out_size, void* d_ws, size_t ws_size,
                              hipStream_t stream) {
  const float* feat = (const float*)d_in[0];
  const float* weight = (const float*)d_in[1];
  const float* bias = (const float*)d_in[2];
  const int* src = (const int*)d_in[3];
  const int* dst = (const int*)d_in[4];
  float* out = (float*)d_out;

  char* ws = (char*)d_ws;
  size_t off = 0;
  auto alloc = [&](size_t bytes) -> void* {
    void* p = ws + off;
    off += (bytes + 511) & ~(size_t)511;
    return p;
  };
  int* deg = (int*)alloc(N_NODES * 4);
  int* cnt = (int*)alloc(N_NODES * 4);
  int* row_off = (int*)alloc((N_NODES + 1) * 4);
  int* cursor = (int*)alloc(N_NODES * 4);
  float* norm = (float*)alloc(N_NODES * 4);
  int* eidx = (int*)alloc(N_EDGES * 4);
  short* Wf = (short*)alloc(IN_F * OUT_F * 2);
  unsigned short* h = (unsigned short*)alloc((size_t)N_NODES * OUT_F * 2);
  int* blockSums = (int*)alloc(SCAN_BLOCKS * 4);
  int* blockOff = (int*)alloc(SCAN_BLOCKS * 4);
  (void)off; (void)ws_size; (void)in_sizes; (void)n_in; (void)out_size;

  hipLaunchKernelGGL(init_kernel, dim3((N_NODES + 255) / 256), dim3(256), 0, stream, deg, cnt);
  hipLaunchKernelGGL(count_kernel, dim3(N_EDGES / 256), dim3(256), 0, stream, src, dst, deg, cnt);
  hipLaunchKernelGGL(blocksum_kernel, dim3(SCAN_BLOCKS), dim3(256), 0, stream, cnt, blockSums);
  hipLaunchKernelGGL(scanblocks_kernel, dim3(1), dim3(64), 0, stream, blockSums, blockOff);
  hipLaunchKernelGGL(csr_kernel, dim3(SCAN_BLOCKS), dim3(256), 0, stream, cnt, deg, blockOff, row_off, cursor, norm);
  hipLaunchKernelGGL(scatter_kernel, dim3(N_EDGES / 256), dim3(256), 0, stream, src, dst, cursor, eidx);
  hipLaunchKernelGGL(wprep_kernel, dim3((IN_F * OUT_F) / 256), dim3(256), 0, stream, weight, Wf);
  hipLaunchKernelGGL(gemm_kernel, dim3((N_NODES + 127) / 128), dim3(256), 0, stream, feat, Wf, norm, h);
  hipLaunchKernelGGL(agg_kernel, dim3(N_NODES / 4), dim3(256), 0, stream, h, row_off, eidx, bias, out);
}

// Round 3
// 256.318 us; speedup vs baseline: 1.7797x; 1.0522x over previous
//
#include <hip/hip_runtime.h>

#define N_NODES 50000
#define N_EDGES 800000
#define IN_F 256
#define OUT_F 128
#define SCAN_BLOCKS 49  // ceil(50000/1024)

#define CHUNKS 32
#define EPC (N_EDGES / CHUNKS)   // 25000 edges per chunk
#define RANGES 4
#define BPR 12500                // bins per range (4*12500 = 50000)

typedef __attribute__((ext_vector_type(8))) short short8;
typedef __attribute__((ext_vector_type(4))) float float4_t;

// float -> bf16 round-to-nearest-even
__device__ __forceinline__ short f2bf(float f) {
  unsigned u = __builtin_bit_cast(unsigned, f);
  u = u + 0x7FFFu + ((u >> 16) & 1u);
  return (short)(u >> 16);
}

// ---- atomic-free histogram: LDS-privatized partial counts ----
// grid 256: b>>7 = which key array (0:dst->pdst, 1:src->psrc), (b>>2)&31 = chunk, b&3 = bin range
__global__ __launch_bounds__(256) void hist_kernel(const int* __restrict__ src,
                                                   const int* __restrict__ dst,
                                                   unsigned short* __restrict__ pdst,
                                                   unsigned short* __restrict__ psrc) {
  __shared__ unsigned bins[BPR];
  int b = blockIdx.x;
  int h = b >> 7;
  int c = (b >> 2) & 31;
  int r = b & 3;
  int rbase = r * BPR;
  int t = threadIdx.x;
  for (int j = t; j < BPR; j += 256) bins[j] = 0;
  __syncthreads();
  const int* key = h ? src : dst;
  int e0 = c * EPC;
  for (int i = t; i < EPC; i += 256) {
    int v = key[e0 + i] - rbase;
    if ((unsigned)v < (unsigned)BPR) atomicAdd(&bins[v], 1u);
  }
  __syncthreads();
  unsigned short* p = (h ? psrc : pdst) + (size_t)c * N_NODES + rbase;
  unsigned* p32 = (unsigned*)p;
  for (int j = t; j < BPR / 2; j += 256) {
    p32[j] = bins[2 * j] | (bins[2 * j + 1] << 16);
  }
}

__global__ __launch_bounds__(256) void reduce_kernel(const unsigned short* __restrict__ pdst,
                                                     const unsigned short* __restrict__ psrc,
                                                     int* __restrict__ cnt,
                                                     int* __restrict__ deg) {
  int v = blockIdx.x * 256 + threadIdx.x;
  if (v >= N_NODES) return;
  int s = 0, g = 0;
#pragma unroll
  for (int c = 0; c < CHUNKS; ++c) {
    s += pdst[(size_t)c * N_NODES + v];
    g += psrc[(size_t)c * N_NODES + v];
  }
  cnt[v] = s;
  deg[v] = g;
}

// ---- 3-phase parallel scan of cnt -> row_off (+ norm from deg) ----
__global__ __launch_bounds__(256) void blocksum_kernel(const int* __restrict__ cnt,
                                                       int* __restrict__ blockSums) {
  int t = threadIdx.x, b = blockIdx.x;
  int base = b * 1024 + t * 4;
  int s = 0;
#pragma unroll
  for (int i = 0; i < 4; ++i) {
    int idx = base + i;
    if (idx < N_NODES) s += cnt[idx];
  }
  for (int off = 32; off > 0; off >>= 1) s += __shfl_down(s, off);
  __shared__ int ws[4];
  int l = t & 63, w = t >> 6;
  if (l == 0) ws[w] = s;
  __syncthreads();
  if (t == 0) blockSums[b] = ws[0] + ws[1] + ws[2] + ws[3];
}

__global__ void scanblocks_kernel(const int* __restrict__ blockSums,
                                  int* __restrict__ blockOff) {
  int l = threadIdx.x;  // 64 threads
  int v = (l < SCAN_BLOCKS) ? blockSums[l] : 0;
  int x = v;
  for (int off = 1; off < 64; off <<= 1) {
    int y = __shfl_up(x, off);
    if (l >= off) x += y;
  }
  if (l < SCAN_BLOCKS) blockOff[l] = x - v;  // exclusive
}

__global__ __launch_bounds__(256) void csr_kernel(const int* __restrict__ cnt,
                                                  const int* __restrict__ deg,
                                                  const int* __restrict__ blockOff,
                                                  int* __restrict__ row_off,
                                                  float* __restrict__ norm) {
  int t = threadIdx.x, b = blockIdx.x;
  int base = b * 1024 + t * 4;
  int v[4];
  int s = 0;
#pragma unroll
  for (int i = 0; i < 4; ++i) {
    int idx = base + i;
    v[i] = (idx < N_NODES) ? cnt[idx] : 0;
    s += v[i];
  }
  int l = t & 63, w = t >> 6;
  int x = s;
  for (int off = 1; off < 64; off <<= 1) {
    int y = __shfl_up(x, off);
    if (l >= off) x += y;
  }
  __shared__ int ws[4];
  if (l == 63) ws[w] = x;
  __syncthreads();
  int wadd = 0;
  for (int i = 0; i < w; ++i) wadd += ws[i];
  int run = blockOff[b] + wadd + x - s;  // exclusive prefix of this thread's chunk
#pragma unroll
  for (int i = 0; i < 4; ++i) {
    int idx = base + i;
    if (idx < N_NODES) {
      row_off[idx] = run;
      run += v[i];
      int dg = deg[idx];
      norm[idx] = 1.0f / (float)(dg > 1 ? dg : 1);
      if (idx == N_NODES - 1) row_off[N_NODES] = run;
    }
  }
}

// per-chunk base cursors: offs[c][v] = row_off[v] + sum_{c'<c} pdst[c'][v]
__global__ __launch_bounds__(256) void offsets_kernel(const unsigned short* __restrict__ pdst,
                                                      const int* __restrict__ row_off,
                                                      int* __restrict__ offs) {
  int v = blockIdx.x * 256 + threadIdx.x;
  if (v >= N_NODES) return;
  int run = row_off[v];
#pragma unroll
  for (int c = 0; c < CHUNKS; ++c) {
    offs[(size_t)c * N_NODES + v] = run;
    run += pdst[(size_t)c * N_NODES + v];
  }
}

// atomic-free scatter: LDS cursor ranks within (chunk, range)
__global__ __launch_bounds__(256) void scatter2_kernel(const int* __restrict__ src,
                                                       const int* __restrict__ dst,
                                                       const int* __restrict__ offs,
                                                       int* __restrict__ eidx) {
  __shared__ unsigned cur[BPR];
  int b = blockIdx.x;  // 0..127
  int c = b >> 2, r = b & 3;
  int rbase = r * BPR;
  int t = threadIdx.x;
  const int* orow = offs + (size_t)c * N_NODES + rbase;
  for (int j = t; j < BPR; j += 256) cur[j] = (unsigned)orow[j];
  __syncthreads();
  int e0 = c * EPC;
  for (int i = t; i < EPC; i += 256) {
    int d = dst[e0 + i] - rbase;
    if ((unsigned)d < (unsigned)BPR) {
      unsigned p = atomicAdd(&cur[d], 1u);
      eidx[p] = src[e0 + i];
    }
  }
}

// W [256][128] fp32 row-major -> bf16 in MFMA B-fragment order:
// Wf[ ((s*8+t)*16 + m)*32 + q*8 + j ]  where k=s*32+q*8+j, n=t*16+m
__global__ void wprep_kernel(const float* __restrict__ W, short* __restrict__ Wf) {
  int idx = blockIdx.x * 256 + threadIdx.x;  // 32768 total
  int k = idx >> 7, n = idx & 127;
  int s = k >> 5, q = (k >> 3) & 3, j = k & 7;
  int t = n >> 4, m = n & 15;
  Wf[(((s * 8 + t) * 16 + m) * 32) + q * 8 + j] = f2bf(W[idx]);
}

// h = (feat @ W) * norm[row], stored as bf16 (ushort). No LDS.
__global__ __launch_bounds__(256) void gemm_kernel(const float* __restrict__ feat,
                                                   const short* __restrict__ Wf,
                                                   const float* __restrict__ norm,
                                                   unsigned short* __restrict__ h) {
  int tid = threadIdx.x;
  int w = tid >> 6, l = tid & 63;
  int m = l & 15, q = l >> 4;
  long base = (long)blockIdx.x * 128 + w * 32;

  float4_t acc[2][8];
#pragma unroll
  for (int r = 0; r < 2; ++r)
#pragma unroll
    for (int t = 0; t < 8; ++t) acc[r][t] = (float4_t)(0.0f);

  long row0 = base + m;
  long row1 = base + 16 + m;
  long r0c = row0 < N_NODES - 1 ? row0 : N_NODES - 1;
  long r1c = row1 < N_NODES - 1 ? row1 : N_NODES - 1;
  const float* a0p = feat + (size_t)r0c * IN_F;
  const float* a1p = feat + (size_t)r1c * IN_F;
  const short8* bb = (const short8*)Wf;

#pragma unroll
  for (int s = 0; s < 8; ++s) {
    int k0 = s * 32 + q * 8;
    float4_t av0a = *(const float4_t*)(a0p + k0);
    float4_t av0b = *(const float4_t*)(a0p + k0 + 4);
    float4_t av1a = *(const float4_t*)(a1p + k0);
    float4_t av1b = *(const float4_t*)(a1p + k0 + 4);
    short8 fa0, fa1;
#pragma unroll
    for (int i = 0; i < 4; ++i) {
      fa0[i] = f2bf(av0a[i]);
      fa0[i + 4] = f2bf(av0b[i]);
      fa1[i] = f2bf(av1a[i]);
      fa1[i + 4] = f2bf(av1b[i]);
    }
#pragma unroll
    for (int t = 0; t < 8; ++t) {
      short8 fb = bb[((s * 8 + t) * 16 + m) * 4 + q];
      acc[0][t] = __builtin_amdgcn_mfma_f32_16x16x32_bf16(fa0, fb, acc[0][t], 0, 0, 0);
      acc[1][t] = __builtin_amdgcn_mfma_f32_16x16x32_bf16(fa1, fb, acc[1][t], 0, 0, 0);
    }
  }

  // C/D layout: col = lane&15 (=m), row = q*4 + i
#pragma unroll
  for (int r = 0; r < 2; ++r) {
#pragma unroll
    for (int i = 0; i < 4; ++i) {
      long row = base + r * 16 + q * 4 + i;
      if (row < N_NODES) {
        float nm = norm[row];
        size_t ho = (size_t)row * OUT_F;
#pragma unroll
        for (int t = 0; t < 8; ++t) {
          h[ho + t * 16 + m] = (unsigned short)f2bf(acc[r][t][i] * nm);
        }
      }
    }
  }
}

// One wave per dst node. Lane covers 2 columns (one uint = 2 bf16 of h row).
__global__ __launch_bounds__(256) void agg_kernel(const unsigned short* __restrict__ h,
                                                  const int* __restrict__ row_off,
                                                  const int* __restrict__ eidx,
                                                  const float* __restrict__ bias,
                                                  float* __restrict__ out) {
  int w = threadIdx.x >> 6, l = threadIdx.x & 63;
  int d = blockIdx.x * 4 + w;  // grid 12500 -> exactly 50000
  int rs = row_off[d], re = row_off[d + 1];
  const unsigned* __restrict__ hu = (const unsigned*)h;  // 64 uints per row
  float a0 = 0.0f, a1 = 0.0f;
  for (int bse = rs; bse < re; bse += 64) {
    int n = re - bse; if (n > 64) n = 64;
    int e = (l < n) ? eidx[bse + l] : 0;
    int j = 0;
    for (; j + 4 <= n; j += 4) {
      int s0 = __shfl(e, j);
      int s1 = __shfl(e, j + 1);
      int s2 = __shfl(e, j + 2);
      int s3 = __shfl(e, j + 3);
      unsigned v0 = hu[(size_t)s0 * 64 + l];
      unsigned v1 = hu[(size_t)s1 * 64 + l];
      unsigned v2 = hu[(size_t)s2 * 64 + l];
      unsigned v3 = hu[(size_t)s3 * 64 + l];
      a0 += __builtin_bit_cast(float, v0 << 16);
      a1 += __builtin_bit_cast(float, v0 & 0xFFFF0000u);
      a0 += __builtin_bit_cast(float, v1 << 16);
      a1 += __builtin_bit_cast(float, v1 & 0xFFFF0000u);
      a0 += __builtin_bit_cast(float, v2 << 16);
      a1 += __builtin_bit_cast(float, v2 & 0xFFFF0000u);
      a0 += __builtin_bit_cast(float, v3 << 16);
      a1 += __builtin_bit_cast(float, v3 & 0xFFFF0000u);
    }
    for (; j < n; ++j) {
      int s0 = __shfl(e, j);
      unsigned v0 = hu[(size_t)s0 * 64 + l];
      a0 += __builtin_bit_cast(float, v0 << 16);
      a1 += __builtin_bit_cast(float, v0 & 0xFFFF0000u);
    }
  }
  float2 b = ((const float2*)bias)[l];
  float2 o;
  o.x = a0 + b.x;
  o.y = a1 + b.y;
  ((float2*)(out + (size_t)d * OUT_F))[l] = o;
}

extern "C" void kernel_launch(void* const* d_in, const int* in_sizes, int n_in,
                              void* d_out, int out_size, void* d_ws, size_t ws_size,
                              hipStream_t stream) {
  const float* feat = (const float*)d_in[0];
  const float* weight = (const float*)d_in[1];
  const float* bias = (const float*)d_in[2];
  const int* src = (const int*)d_in[3];
  const int* dst = (const int*)d_in[4];
  float* out = (float*)d_out;

  char* ws = (char*)d_ws;
  size_t off = 0;
  auto alloc = [&](size_t bytes) -> void* {
    void* p = ws + off;
    off += (bytes + 511) & ~(size_t)511;
    return p;
  };
  int* deg = (int*)alloc(N_NODES * 4);
  int* cnt = (int*)alloc(N_NODES * 4);
  int* row_off = (int*)alloc((N_NODES + 1) * 4);
  float* norm = (float*)alloc(N_NODES * 4);
  int* eidx = (int*)alloc(N_EDGES * 4);
  short* Wf = (short*)alloc(IN_F * OUT_F * 2);
  unsigned short* h = (unsigned short*)alloc((size_t)N_NODES * OUT_F * 2);
  int* blockSums = (int*)alloc(SCAN_BLOCKS * 4);
  int* blockOff = (int*)alloc(SCAN_BLOCKS * 4);
  unsigned short* pdst = (unsigned short*)alloc((size_t)CHUNKS * N_NODES * 2);
  unsigned short* psrc = (unsigned short*)alloc((size_t)CHUNKS * N_NODES * 2);
  int* offs = (int*)alloc((size_t)CHUNKS * N_NODES * 4);
  (void)off; (void)ws_size; (void)in_sizes; (void)n_in; (void)out_size;

  hipLaunchKernelGGL(hist_kernel, dim3(2 * CHUNKS * RANGES), dim3(256), 0, stream, src, dst, pdst, psrc);
  hipLaunchKernelGGL(reduce_kernel, dim3((N_NODES + 255) / 256), dim3(256), 0, stream, pdst, psrc, cnt, deg);
  hipLaunchKernelGGL(blocksum_kernel, dim3(SCAN_BLOCKS), dim3(256), 0, stream, cnt, blockSums);
  hipLaunchKernelGGL(scanblocks_kernel, dim3(1), dim3(64), 0, stream, blockSums, blockOff);
  hipLaunchKernelGGL(csr_kernel, dim3(SCAN_BLOCKS), dim3(256), 0, stream, cnt, deg, blockOff, row_off, norm);
  hipLaunchKernelGGL(offsets_kernel, dim3((N_NODES + 255) / 256), dim3(256), 0, stream, pdst, row_off, offs);
  hipLaunchKernelGGL(scatter2_kernel, dim3(CHUNKS * RANGES), dim3(256), 0, stream, src, dst, offs, eidx);
  hipLaunchKernelGGL(wprep_kernel, dim3((IN_F * OUT_F) / 256), dim3(256), 0, stream, weight, Wf);
  hipLaunchKernelGGL(gemm_kernel, dim3((N_NODES + 127) / 128), dim3(256), 0, stream, feat, Wf, norm, h);
  hipLaunchKernelGGL(agg_kernel, dim3(N_NODES / 4), dim3(256), 0, stream, h, row_off, eidx, bias, out);
}

// Round 4
// 216.914 us; speedup vs baseline: 2.1030x; 1.1817x over previous
//
#include <hip/hip_runtime.h>

#define N_NODES 50000
#define N_EDGES 800000
#define IN_F 256
#define OUT_F 128
#define SCAN_BLOCKS 49  // ceil(50000/1024)

#define CHUNKS 64
#define EPC (N_EDGES / CHUNKS)   // 12500 edges per chunk (12500 % 4 == 0)
#define RANGES 2
#define BPR 25000                // bins per range (2*25000 = 50000)
#define BPRW (BPR / 2)           // packed u32 words (2 x u16 bins each)

typedef __attribute__((ext_vector_type(8))) short short8;
typedef __attribute__((ext_vector_type(4))) float float4_t;

// float -> bf16 round-to-nearest-even
__device__ __forceinline__ short f2bf(float f) {
  unsigned u = __builtin_bit_cast(unsigned, f);
  u = u + 0x7FFFu + ((u >> 16) & 1u);
  return (short)(u >> 16);
}

// ---- histogram + per-edge rank: LDS-privatized, packed 2xu16 bins ----
// grid 256: b>>7 = side (0: dst, 1: src), (b>>1)&63 = chunk, b&1 = bin range
__global__ __launch_bounds__(256) void hist_kernel(const int* __restrict__ src,
                                                   const int* __restrict__ dst,
                                                   unsigned short* __restrict__ pdst,
                                                   unsigned short* __restrict__ psrc,
                                                   unsigned short* __restrict__ rank16) {
  __shared__ unsigned bins[BPRW];
  int b = blockIdx.x;
  int h = b >> 7;
  int c = (b >> 1) & 63;
  int r = b & 1;
  int rbase = r * BPR;
  int t = threadIdx.x;
  for (int j = t; j < BPRW; j += 256) bins[j] = 0;
  __syncthreads();
  const int* key = h ? src : dst;
  int e0 = c * EPC;
  for (int i = t; i < EPC; i += 256) {
    int v = key[e0 + i] - rbase;
    if ((unsigned)v < (unsigned)BPR) {
      unsigned sh = (v & 1) * 16;
      unsigned old = atomicAdd(&bins[v >> 1], 1u << sh);
      if (!h) rank16[e0 + i] = (unsigned short)((old >> sh) & 0xFFFFu);
    }
  }
  __syncthreads();
  unsigned* p32 = (unsigned*)((h ? psrc : pdst) + (size_t)c * N_NODES + rbase);
  for (int j = t; j < BPRW; j += 256) p32[j] = bins[j];
}

__global__ __launch_bounds__(256) void reduce_kernel(const unsigned short* __restrict__ pdst,
                                                     const unsigned short* __restrict__ psrc,
                                                     int* __restrict__ cnt,
                                                     int* __restrict__ deg) {
  int v = blockIdx.x * 256 + threadIdx.x;
  if (v >= N_NODES) return;
  int s = 0, g = 0;
#pragma unroll
  for (int c = 0; c < CHUNKS; ++c) {
    s += pdst[(size_t)c * N_NODES + v];
    g += psrc[(size_t)c * N_NODES + v];
  }
  cnt[v] = s;
  deg[v] = g;
}

// ---- 3-phase parallel scan of cnt -> row_off (+ norm from deg) ----
__global__ __launch_bounds__(256) void blocksum_kernel(const int* __restrict__ cnt,
                                                       int* __restrict__ blockSums) {
  int t = threadIdx.x, b = blockIdx.x;
  int base = b * 1024 + t * 4;
  int s = 0;
#pragma unroll
  for (int i = 0; i < 4; ++i) {
    int idx = base + i;
    if (idx < N_NODES) s += cnt[idx];
  }
  for (int off = 32; off > 0; off >>= 1) s += __shfl_down(s, off);
  __shared__ int ws[4];
  int l = t & 63, w = t >> 6;
  if (l == 0) ws[w] = s;
  __syncthreads();
  if (t == 0) blockSums[b] = ws[0] + ws[1] + ws[2] + ws[3];
}

__global__ void scanblocks_kernel(const int* __restrict__ blockSums,
                                  int* __restrict__ blockOff) {
  int l = threadIdx.x;  // 64 threads
  int v = (l < SCAN_BLOCKS) ? blockSums[l] : 0;
  int x = v;
  for (int off = 1; off < 64; off <<= 1) {
    int y = __shfl_up(x, off);
    if (l >= off) x += y;
  }
  if (l < SCAN_BLOCKS) blockOff[l] = x - v;  // exclusive
}

__global__ __launch_bounds__(256) void csr_kernel(const int* __restrict__ cnt,
                                                  const int* __restrict__ deg,
                                                  const int* __restrict__ blockOff,
                                                  int* __restrict__ row_off,
                                                  float* __restrict__ norm) {
  int t = threadIdx.x, b = blockIdx.x;
  int base = b * 1024 + t * 4;
  int v[4];
  int s = 0;
#pragma unroll
  for (int i = 0; i < 4; ++i) {
    int idx = base + i;
    v[i] = (idx < N_NODES) ? cnt[idx] : 0;
    s += v[i];
  }
  int l = t & 63, w = t >> 6;
  int x = s;
  for (int off = 1; off < 64; off <<= 1) {
    int y = __shfl_up(x, off);
    if (l >= off) x += y;
  }
  __shared__ int ws[4];
  if (l == 63) ws[w] = x;
  __syncthreads();
  int wadd = 0;
  for (int i = 0; i < w; ++i) wadd += ws[i];
  int run = blockOff[b] + wadd + x - s;  // exclusive prefix of this thread's chunk
#pragma unroll
  for (int i = 0; i < 4; ++i) {
    int idx = base + i;
    if (idx < N_NODES) {
      row_off[idx] = run;
      run += v[i];
      int dg = deg[idx];
      norm[idx] = 1.0f / (float)(dg > 1 ? dg : 1);
      if (idx == N_NODES - 1) row_off[N_NODES] = run;
    }
  }
}

// per-chunk base cursors: offs[c][v] = row_off[v] + sum_{c'<c} pdst[c'][v]
__global__ __launch_bounds__(256) void offsets_kernel(const unsigned short* __restrict__ pdst,
                                                      const int* __restrict__ row_off,
                                                      int* __restrict__ offs) {
  int v = blockIdx.x * 256 + threadIdx.x;
  if (v >= N_NODES) return;
  int run = row_off[v];
#pragma unroll
  for (int c = 0; c < CHUNKS; ++c) {
    offs[(size_t)c * N_NODES + v] = run;
    run += pdst[(size_t)c * N_NODES + v];
  }
}

// stateless streaming scatter: pos = offs[chunk][dst[e]] + rank16[e]
__global__ __launch_bounds__(256) void scatter3_kernel(const int* __restrict__ src,
                                                       const int* __restrict__ dst,
                                                       const int* __restrict__ offs,
                                                       const unsigned short* __restrict__ rank16,
                                                       int* __restrict__ eidx) {
  int tid = blockIdx.x * 256 + threadIdx.x;
  int e = tid * 4;
  if (e >= N_EDGES) return;
  int4 d4 = *(const int4*)(dst + e);
  int4 s4 = *(const int4*)(src + e);
  uint2 rr = *(const uint2*)(rank16 + e);
  int c = e / EPC;  // 4-edge group never straddles a chunk (EPC % 4 == 0)
  const int* base = offs + (size_t)c * N_NODES;
  eidx[base[d4.x] + (rr.x & 0xFFFFu)] = s4.x;
  eidx[base[d4.y] + (rr.x >> 16)] = s4.y;
  eidx[base[d4.z] + (rr.y & 0xFFFFu)] = s4.z;
  eidx[base[d4.w] + (rr.y >> 16)] = s4.w;
}

// W [256][128] fp32 row-major -> bf16 in MFMA B-fragment order:
// Wf[ ((s*8+t)*16 + m)*32 + q*8 + j ]  where k=s*32+q*8+j, n=t*16+m
__global__ void wprep_kernel(const float* __restrict__ W, short* __restrict__ Wf) {
  int idx = blockIdx.x * 256 + threadIdx.x;  // 32768 total
  int k = idx >> 7, n = idx & 127;
  int s = k >> 5, q = (k >> 3) & 3, j = k & 7;
  int t = n >> 4, m = n & 15;
  Wf[(((s * 8 + t) * 16 + m) * 32) + q * 8 + j] = f2bf(W[idx]);
}

// h = (feat @ W) * norm[row], stored as bf16 (ushort). No LDS.
__global__ __launch_bounds__(256) void gemm_kernel(const float* __restrict__ feat,
                                                   const short* __restrict__ Wf,
                                                   const float* __restrict__ norm,
                                                   unsigned short* __restrict__ h) {
  int tid = threadIdx.x;
  int w = tid >> 6, l = tid & 63;
  int m = l & 15, q = l >> 4;
  long base = (long)blockIdx.x * 128 + w * 32;

  float4_t acc[2][8];
#pragma unroll
  for (int r = 0; r < 2; ++r)
#pragma unroll
    for (int t = 0; t < 8; ++t) acc[r][t] = (float4_t)(0.0f);

  long row0 = base + m;
  long row1 = base + 16 + m;
  long r0c = row0 < N_NODES - 1 ? row0 : N_NODES - 1;
  long r1c = row1 < N_NODES - 1 ? row1 : N_NODES - 1;
  const float* a0p = feat + (size_t)r0c * IN_F;
  const float* a1p = feat + (size_t)r1c * IN_F;
  const short8* bb = (const short8*)Wf;

#pragma unroll
  for (int s = 0; s < 8; ++s) {
    int k0 = s * 32 + q * 8;
    float4_t av0a = *(const float4_t*)(a0p + k0);
    float4_t av0b = *(const float4_t*)(a0p + k0 + 4);
    float4_t av1a = *(const float4_t*)(a1p + k0);
    float4_t av1b = *(const float4_t*)(a1p + k0 + 4);
    short8 fa0, fa1;
#pragma unroll
    for (int i = 0; i < 4; ++i) {
      fa0[i] = f2bf(av0a[i]);
      fa0[i + 4] = f2bf(av0b[i]);
      fa1[i] = f2bf(av1a[i]);
      fa1[i + 4] = f2bf(av1b[i]);
    }
#pragma unroll
    for (int t = 0; t < 8; ++t) {
      short8 fb = bb[((s * 8 + t) * 16 + m) * 4 + q];
      acc[0][t] = __builtin_amdgcn_mfma_f32_16x16x32_bf16(fa0, fb, acc[0][t], 0, 0, 0);
      acc[1][t] = __builtin_amdgcn_mfma_f32_16x16x32_bf16(fa1, fb, acc[1][t], 0, 0, 0);
    }
  }

  // C/D layout: col = lane&15 (=m), row = q*4 + i
#pragma unroll
  for (int r = 0; r < 2; ++r) {
#pragma unroll
    for (int i = 0; i < 4; ++i) {
      long row = base + r * 16 + q * 4 + i;
      if (row < N_NODES) {
        float nm = norm[row];
        size_t ho = (size_t)row * OUT_F;
#pragma unroll
        for (int t = 0; t < 8; ++t) {
          h[ho + t * 16 + m] = (unsigned short)f2bf(acc[r][t][i] * nm);
        }
      }
    }
  }
}

// One wave per dst node. Lane covers 2 columns (one uint = 2 bf16 of h row).
__global__ __launch_bounds__(256) void agg_kernel(const unsigned short* __restrict__ h,
                                                  const int* __restrict__ row_off,
                                                  const int* __restrict__ eidx,
                                                  const float* __restrict__ bias,
                                                  float* __restrict__ out) {
  int w = threadIdx.x >> 6, l = threadIdx.x & 63;
  int d = blockIdx.x * 4 + w;  // grid 12500 -> exactly 50000
  int rs = row_off[d], re = row_off[d + 1];
  const unsigned* __restrict__ hu = (const unsigned*)h;  // 64 uints per row
  float a0 = 0.0f, a1 = 0.0f;
  for (int bse = rs; bse < re; bse += 64) {
    int n = re - bse; if (n > 64) n = 64;
    int e = (l < n) ? eidx[bse + l] : 0;
    int j = 0;
    for (; j + 4 <= n; j += 4) {
      int s0 = __shfl(e, j);
      int s1 = __shfl(e, j + 1);
      int s2 = __shfl(e, j + 2);
      int s3 = __shfl(e, j + 3);
      unsigned v0 = hu[(size_t)s0 * 64 + l];
      unsigned v1 = hu[(size_t)s1 * 64 + l];
      unsigned v2 = hu[(size_t)s2 * 64 + l];
      unsigned v3 = hu[(size_t)s3 * 64 + l];
      a0 += __builtin_bit_cast(float, v0 << 16);
      a1 += __builtin_bit_cast(float, v0 & 0xFFFF0000u);
      a0 += __builtin_bit_cast(float, v1 << 16);
      a1 += __builtin_bit_cast(float, v1 & 0xFFFF0000u);
      a0 += __builtin_bit_cast(float, v2 << 16);
      a1 += __builtin_bit_cast(float, v2 & 0xFFFF0000u);
      a0 += __builtin_bit_cast(float, v3 << 16);
      a1 += __builtin_bit_cast(float, v3 & 0xFFFF0000u);
    }
    for (; j < n; ++j) {
      int s0 = __shfl(e, j);
      unsigned v0 = hu[(size_t)s0 * 64 + l];
      a0 += __builtin_bit_cast(float, v0 << 16);
      a1 += __builtin_bit_cast(float, v0 & 0xFFFF0000u);
    }
  }
  float2 b = ((const float2*)bias)[l];
  float2 o;
  o.x = a0 + b.x;
  o.y = a1 + b.y;
  ((float2*)(out + (size_t)d * OUT_F))[l] = o;
}

extern "C" void kernel_launch(void* const* d_in, const int* in_sizes, int n_in,
                              void* d_out, int out_size, void* d_ws, size_t ws_size,
                              hipStream_t stream) {
  const float* feat = (const float*)d_in[0];
  const float* weight = (const float*)d_in[1];
  const float* bias = (const float*)d_in[2];
  const int* src = (const int*)d_in[3];
  const int* dst = (const int*)d_in[4];
  float* out = (float*)d_out;

  char* ws = (char*)d_ws;
  size_t off = 0;
  auto alloc = [&](size_t bytes) -> void* {
    void* p = ws + off;
    off += (bytes + 511) & ~(size_t)511;
    return p;
  };
  int* deg = (int*)alloc(N_NODES * 4);
  int* cnt = (int*)alloc(N_NODES * 4);
  int* row_off = (int*)alloc((N_NODES + 1) * 4);
  float* norm = (float*)alloc(N_NODES * 4);
  int* eidx = (int*)alloc(N_EDGES * 4);
  short* Wf = (short*)alloc(IN_F * OUT_F * 2);
  unsigned short* h = (unsigned short*)alloc((size_t)N_NODES * OUT_F * 2);
  int* blockSums = (int*)alloc(SCAN_BLOCKS * 4);
  int* blockOff = (int*)alloc(SCAN_BLOCKS * 4);
  unsigned short* pdst = (unsigned short*)alloc((size_t)CHUNKS * N_NODES * 2);
  unsigned short* psrc = (unsigned short*)alloc((size_t)CHUNKS * N_NODES * 2);
  int* offs = (int*)alloc((size_t)CHUNKS * N_NODES * 4);
  unsigned short* rank16 = (unsigned short*)alloc((size_t)N_EDGES * 2);
  (void)off; (void)ws_size; (void)in_sizes; (void)n_in; (void)out_size;

  hipLaunchKernelGGL(hist_kernel, dim3(2 * CHUNKS * RANGES), dim3(256), 0, stream, src, dst, pdst, psrc, rank16);
  hipLaunchKernelGGL(reduce_kernel, dim3((N_NODES + 255) / 256), dim3(256), 0, stream, pdst, psrc, cnt, deg);
  hipLaunchKernelGGL(blocksum_kernel, dim3(SCAN_BLOCKS), dim3(256), 0, stream, cnt, blockSums);
  hipLaunchKernelGGL(scanblocks_kernel, dim3(1), dim3(64), 0, stream, blockSums, blockOff);
  hipLaunchKernelGGL(csr_kernel, dim3(SCAN_BLOCKS), dim3(256), 0, stream, cnt, deg, blockOff, row_off, norm);
  hipLaunchKernelGGL(offsets_kernel, dim3((N_NODES + 255) / 256), dim3(256), 0, stream, pdst, row_off, offs);
  hipLaunchKernelGGL(scatter3_kernel, dim3((N_EDGES / 4 + 255) / 256), dim3(256), 0, stream, src, dst, offs, rank16, eidx);
  hipLaunchKernelGGL(wprep_kernel, dim3((IN_F * OUT_F) / 256), dim3(256), 0, stream, weight, Wf);
  hipLaunchKernelGGL(gemm_kernel, dim3((N_NODES + 127) / 128), dim3(256), 0, stream, feat, Wf, norm, h);
  hipLaunchKernelGGL(agg_kernel, dim3(N_NODES / 4), dim3(256), 0, stream, h, row_off, eidx, bias, out);
}